// Round 10
// baseline (308.197 us; speedup 1.0000x reference)
//
#include <hip/hip_runtime.h>
#include <stdint.h>

// ---------------------------------------------------------------------------
// EdgeNodeGCN on MI355X (gfx950). Inputs fp32, edge_index int32, output fp32.
// Factorization:
//   P[n]  = x[n] @ (Wa - Wb) + b_edge   (Wa = W_edge[0:128], Wb = W_edge[128:256])
//   Q[n]  = x[n] @ Wb
//   msg(e)= relu(P[dst] + Q[src]);  edge_agg[d] = sum msg
//   XA[d] = sum_{e->d} x[src]           (segment_sum commutes with @W_node)
//   nodes = relu(XA @ W_node + b_node); edges = relu(edge_agg @ W_ed + b_ed)
//   out   = sigmoid(relu([nodes|edges] @ W_f1 + b_f1) @ W_f2 + b_f2)
//
// R10 vs R9 (306 us; k_tail 78 us, LDS 50KB/block -> 3 blocks/CU, occ 20%):
//   - k_tail: h never materialized. Per ks (32 h-cols) stream through tiny
//     per-wave dbuf staging [16][40] (2.5KB/wave; block 10KB) and MFMA into
//     persistent final accumulators. Occupancy cap removed.
//   - k_gather: 4 chains/wave (16 lanes each, 32B contiguous Q per lane) —
//     2x memory-level parallelism on the pointer chase.
// Dispatches: convert, sg (list-build + GEMM1 interleaved), gather, tail.
// ---------------------------------------------------------------------------

typedef short short8 __attribute__((ext_vector_type(8)));
typedef float f32x4 __attribute__((ext_vector_type(4)));
typedef float float4v __attribute__((ext_vector_type(4)));
typedef unsigned short us8 __attribute__((ext_vector_type(8)));
typedef unsigned short us4 __attribute__((ext_vector_type(4)));

__device__ inline float bf2f(unsigned short h) {
    union { unsigned int u; float f; } v;
    v.u = ((unsigned int)h) << 16;
    return v.f;
}
__device__ inline unsigned short f2bf(float f) {
    union { float f; unsigned int u; } v;
    v.f = f;
    unsigned int r = v.u + 0x7FFFu + ((v.u >> 16) & 1u);  // RNE
    return (unsigned short)(r >> 16);
}

// ---- convert x + weights(col-major) -> bf16; head[] = -1 ------------------
__global__ __launch_bounds__(256) void k_convert(
    const float* __restrict__ x, const float* __restrict__ W_edge,
    const float* __restrict__ W_node, const float* __restrict__ W_ed,
    const float* __restrict__ W_f1,
    unsigned short* __restrict__ xb, unsigned short* __restrict__ WE2T,
    unsigned short* __restrict__ WnT, unsigned short* __restrict__ WdT,
    unsigned short* __restrict__ Wf1T, int* __restrict__ head,
    int quads, int N)
{
    int i = blockIdx.x * 256 + threadIdx.x;
    if (i < quads) {
        float4v v = ((const float4v*)x)[i];
        us4 o;
        for (int j = 0; j < 4; ++j) o[j] = f2bf(v[j]);
        ((us4*)xb)[i] = o;
        return;
    }
    int j = i - quads;
    if (j < 65536) {                          // WE2T [512 c][128 k] = [Wa-Wb|Wb]^T
        int c = j & 511, k = j >> 9;
        float v;
        if (c < 256) v = W_edge[k * 256 + c] - W_edge[(k + 128) * 256 + c];
        else         v = W_edge[(k + 128) * 256 + (c - 256)];
        WE2T[c * 128 + k] = f2bf(v);
    } else if (j < 65536 + 32768) {           // WnT [256 c][128 k]
        int t = j - 65536;
        int c = t & 255, k = t >> 8;
        WnT[c * 128 + k] = f2bf(W_node[k * 256 + c]);
    } else if (j < 65536 + 65536) {           // WdT [128 c][256 k]
        int t = j - 65536 - 32768;
        int c = t & 127, k = t >> 7;
        WdT[c * 256 + k] = f2bf(W_ed[k * 128 + c]);
    } else if (j < 143360) {                  // Wf1T [32 c][384 k]
        int t = j - 65536 - 65536;
        int c = t & 31, k = t >> 5;
        Wf1T[c * 384 + k] = f2bf(W_f1[k * 32 + c]);
    } else {
        int t = j - 143360;
        if (t < N) head[t] = -1;
    }
}

// ---- fused dispatch: linked-list build (1/3 of blocks) + GEMM1 (2/3) ------
__global__ __launch_bounds__(512) void k_sg(
    const int* __restrict__ src, const int* __restrict__ dst,
    int* __restrict__ head, unsigned long long* __restrict__ next2,
    const unsigned short* __restrict__ xb,     // [N][128] bf16
    const unsigned short* __restrict__ WE2T,   // [512][128] bf16 col-major
    const float* __restrict__ b_edge,          // [256] fp32
    unsigned short* __restrict__ T,            // [N][512]
    int E, int N, int row_tiles, int scat_blocks, int gemm_blocks)
{
    __shared__ unsigned short st[2][16 * 132];
    int b = blockIdx.x;
    if (b % 3 == 2) {                          // linked-list pass
        int sb_id = b / 3;
        if (sb_id >= scat_blocks) return;
        int i = sb_id * 512 + threadIdx.x;
        if (i >= E) return;
        int s = src[i], d = dst[i];
        if ((unsigned)d >= (unsigned)N || (unsigned)s >= (unsigned)N) return;
        int old = atomicExch(&head[d], i);
        next2[i] = ((unsigned long long)(unsigned)s << 32) | (unsigned)old;
        return;
    }
    int g = b - b / 3;                         // gemm block id
    if (g >= gemm_blocks) return;
    int gx = g >> 2;                           // row group (8 tiles)
    int gy = g & 3;                            // col quarter (128 cols)

    const int lane = threadIdx.x & 63;
    const int wave = threadIdx.x >> 6;
    const int quad = lane >> 4;
    const int col16 = lane & 15;
    const int lcol = wave * 16 + col16;        // 0..127
    const int col = gy * 128 + lcol;           // 0..511

    float bias = (col < 256) ? b_edge[col] : 0.f;

    short8 bf[4];
    for (int ks = 0; ks < 4; ++ks)
        bf[ks] = *(const short8*)(WE2T + (size_t)col * 128 + ks * 32 + quad * 8);

    const int tid = threadIdx.x;
    const int srow = tid >> 5;                 // 0..15
    const int sc4 = (tid & 31) * 4;            // 0..124

    for (int t = 0; t < 8; ++t) {
        int tile = gx * 8 + t;
        if (tile >= row_tiles) break;          // block-uniform
        int r0 = tile * 16;
        f32x4 acc = {0.f, 0.f, 0.f, 0.f};
        const unsigned short* ap = xb + (size_t)(r0 + col16) * 128 + quad * 8;
        for (int ks = 0; ks < 4; ++ks) {
            short8 a = *(const short8*)(ap + ks * 32);
            acc = __builtin_amdgcn_mfma_f32_16x16x32_bf16(a, bf[ks], acc, 0, 0, 0);
        }
        unsigned short* sbuf = st[t & 1];
        for (int r = 0; r < 4; ++r)
            sbuf[(quad * 4 + r) * 132 + lcol] = f2bf(acc[r] + bias);
        __syncthreads();
        us4 v = *(const us4*)(sbuf + srow * 132 + sc4);
        *(us4*)(T + (size_t)(r0 + srow) * 512 + gy * 128 + sc4) = v;
    }
}

// ---- Gather: 4 chains per wave (16 lanes each), linked-list walk ----------
__global__ __launch_bounds__(256) void k_gather(
    unsigned short* __restrict__ T,          // [N][512]: P|Q -> EA over P
    const unsigned short* __restrict__ xb,   // [N][128]
    unsigned short* __restrict__ XA,         // [N][128]
    const int* __restrict__ head,
    const unsigned long long* __restrict__ next2, int N)
{
    int wave = threadIdx.x >> 6;
    int lane = threadIdx.x & 63;
    int qtr = lane >> 4;                      // chain select 0..3
    int c = lane & 15;                        // lane within chain
    int n = blockIdx.x * 16 + wave * 4 + qtr;
    bool act = n < N;
    int nn = act ? n : N - 1;
    int c16 = c * 16;                         // Q/EA col base (32 B/lane)
    int c8 = c * 8;                           // x col base (16 B/lane)

    us8 pv0 = *(const us8*)(T + (size_t)nn * 512 + c16);
    us8 pv1 = *(const us8*)(T + (size_t)nn * 512 + c16 + 8);
    float p[16];
    for (int j = 0; j < 8; ++j) { p[j] = bf2f(pv0[j]); p[8 + j] = bf2f(pv1[j]); }
    float aE[16];
    for (int j = 0; j < 16; ++j) aE[j] = 0.f;
    float aX[8];
    for (int j = 0; j < 8; ++j) aX[j] = 0.f;

    int cur = act ? head[n] : -1;
    while (__any(cur >= 0)) {
        bool v = cur >= 0;
        int safe = v ? cur : 0;
        unsigned long long e2 = next2[safe];   // broadcast within chain
        int s = (int)(e2 >> 32);
        float m = v ? 1.f : 0.f;
        const unsigned short* tb = T + (size_t)s * 512 + 256;
        us8 q0 = *(const us8*)(tb + c16);
        us8 q1 = *(const us8*)(tb + c16 + 8);
        us8 xv = *(const us8*)(xb + (size_t)s * 128 + c8);
        for (int j = 0; j < 8; ++j) {
            aE[j]     += m * fmaxf(p[j]     + bf2f(q0[j]), 0.f);
            aE[8 + j] += m * fmaxf(p[8 + j] + bf2f(q1[j]), 0.f);
            aX[j]     += m * bf2f(xv[j]);
        }
        cur = v ? (int)(unsigned)(e2 & 0xFFFFFFFFull) : -1;
    }
    if (act) {
        us8 e0, e1, xo;
        for (int j = 0; j < 8; ++j) {
            e0[j] = f2bf(aE[j]);
            e1[j] = f2bf(aE[8 + j]);
            xo[j] = f2bf(aX[j]);
        }
        *(us8*)(T + (size_t)n * 512 + c16) = e0;       // EA over own P: safe
        *(us8*)(T + (size_t)n * 512 + c16 + 8) = e1;
        *(us8*)(XA + (size_t)n * 128 + c8) = xo;
    }
}

// ---- Fused tail: stream h through tiny staging; final acc persistent ------
// One wave per 16-row tile. Per ks (32 h-cols): compute C-frag pair, relu,
// write [16][40] staging (dbuf), read back as A-frag, MFMA into facc0/1.
__global__ __launch_bounds__(256) void k_tail(
    const unsigned short* __restrict__ T,    // EA in cols 0-255
    const unsigned short* __restrict__ XA,   // [N][128]
    const unsigned short* __restrict__ WnT,  // [256][128] col-major
    const unsigned short* __restrict__ WdT,  // [128][256] col-major
    const unsigned short* __restrict__ Wf1T, // [32][384] col-major
    const float* __restrict__ b_node, const float* __restrict__ b_ed,
    const float* __restrict__ b_f1, const float* __restrict__ W_f2,
    const float* __restrict__ b_f2,
    float* __restrict__ out, int N, int row_tiles)
{
    __shared__ unsigned short stg[4][2][16 * 40];
    const int wave = threadIdx.x >> 6;
    const int lane = threadIdx.x & 63;
    const int quad = lane >> 4;
    const int col16 = lane & 15;
    int tile = blockIdx.x * 4 + wave;
    if (tile >= row_tiles) return;            // wave-local LDS: no barrier needed
    int r0 = tile * 16;

    int arow = r0 + col16;
    if (arow >= N) arow = N - 1;              // clamp A-loads; stores guarded

    short8 ax[4];
    {
        const unsigned short* xap = XA + (size_t)arow * 128 + quad * 8;
        for (int ks = 0; ks < 4; ++ks) ax[ks] = *(const short8*)(xap + ks * 32);
    }
    short8 ae[8];
    {
        const unsigned short* eap = T + (size_t)arow * 512 + quad * 8;
        for (int ks = 0; ks < 8; ++ks) ae[ks] = *(const short8*)(eap + ks * 32);
    }

    f32x4 facc0 = {0.f, 0.f, 0.f, 0.f}, facc1 = {0.f, 0.f, 0.f, 0.f};

    for (int ks = 0; ks < 12; ++ks) {
        unsigned short* sb = &stg[wave][ks & 1][0];
        for (int h = 0; h < 2; ++h) {
            int lcol = h * 16 + col16;         // 0..31 within ks group
            f32x4 acc = {0.f, 0.f, 0.f, 0.f};
            float bias;
            if (ks < 8) {                      // nodes: h-cols 0..255
                int cn = ks * 32 + lcol;
                const unsigned short* wp = WnT + (size_t)cn * 128 + quad * 8;
                for (int k4 = 0; k4 < 4; ++k4) {
                    short8 bfr = *(const short8*)(wp + k4 * 32);
                    acc = __builtin_amdgcn_mfma_f32_16x16x32_bf16(ax[k4], bfr, acc, 0, 0, 0);
                }
                bias = b_node[cn];
            } else {                           // edges: h-cols 256..383
                int ce = (ks - 8) * 32 + lcol;
                const unsigned short* wp = WdT + (size_t)ce * 256 + quad * 8;
                for (int k8 = 0; k8 < 8; ++k8) {
                    short8 bfr = *(const short8*)(wp + k8 * 32);
                    acc = __builtin_amdgcn_mfma_f32_16x16x32_bf16(ae[k8], bfr, acc, 0, 0, 0);
                }
                bias = b_ed[ce];
            }
            for (int r = 0; r < 4; ++r)
                sb[(quad * 4 + r) * 40 + lcol] = f2bf(fmaxf(acc[r] + bias, 0.f));
        }
        // read back as A-frag (row=col16, k=quad*8+j) and fold into final acc
        short8 a = *(const short8*)(sb + col16 * 40 + quad * 8);
        short8 ba = *(const short8*)(Wf1T + (size_t)col16 * 384 + ks * 32 + quad * 8);
        short8 bb = *(const short8*)(Wf1T + (size_t)(col16 + 16) * 384 + ks * 32 + quad * 8);
        facc0 = __builtin_amdgcn_mfma_f32_16x16x32_bf16(a, ba, facc0, 0, 0, 0);
        facc1 = __builtin_amdgcn_mfma_f32_16x16x32_bf16(a, bb, facc1, 0, 0, 0);
    }

    float f1a = b_f1[col16], f1b = b_f1[16 + col16];
    float w2a = W_f2[col16], w2b = W_f2[16 + col16];
    float b2 = b_f2[0];
    float s[4];
    for (int r = 0; r < 4; ++r)
        s[r] = fmaxf(facc0[r] + f1a, 0.f) * w2a + fmaxf(facc1[r] + f1b, 0.f) * w2b;
    for (int m = 1; m < 16; m <<= 1)
        for (int r = 0; r < 4; ++r) s[r] += __shfl_xor(s[r], m, 64);
    if (col16 == 0) {
        int orow = r0 + quad * 4;
        for (int r = 0; r < 4; ++r) {
            if (orow + r < N) {
                float v = s[r] + b2;
                out[orow + r] = 1.f / (1.f + __expf(-v));
            }
        }
    }
}

extern "C" void kernel_launch(void* const* d_in, const int* in_sizes, int n_in,
                              void* d_out, int out_size, void* d_ws, size_t ws_size,
                              hipStream_t stream) {
    const float* x      = (const float*)d_in[0];
    const int*   ei     = (const int*)d_in[1];
    // d_in[2] = e (unused)
    const float* W_node = (const float*)d_in[3];
    const float* b_node = (const float*)d_in[4];
    const float* W_edge = (const float*)d_in[5];
    const float* b_edge = (const float*)d_in[6];
    const float* W_ed   = (const float*)d_in[7];
    const float* b_ed   = (const float*)d_in[8];
    const float* W_f1   = (const float*)d_in[9];
    const float* b_f1   = (const float*)d_in[10];
    const float* W_f2   = (const float*)d_in[11];
    const float* b_f2   = (const float*)d_in[12];

    const int N = in_sizes[0] / 128;
    const int E = in_sizes[1] / 2;
    const int* src = ei;
    const int* dst = ei + E;

    char* ws = (char*)d_ws;
    size_t off = 0;
    auto alloc = [&](size_t bytes) { size_t o = off; off += (bytes + 255) & ~(size_t)255; return o; };
    unsigned short* xb   = (unsigned short*)(ws + alloc((size_t)N * 128 * 2));
    unsigned short* WE2T = (unsigned short*)(ws + alloc(512 * 128 * 2));
    unsigned short* WnT  = (unsigned short*)(ws + alloc(256 * 128 * 2));
    unsigned short* WdT  = (unsigned short*)(ws + alloc(128 * 256 * 2));
    unsigned short* Wf1T = (unsigned short*)(ws + alloc(32 * 384 * 2));
    unsigned short* T    = (unsigned short*)(ws + alloc((size_t)N * 512 * 2));
    unsigned short* XA   = (unsigned short*)(ws + alloc((size_t)N * 128 * 2));
    int* head            = (int*)(ws + alloc((size_t)N * 4));
    unsigned long long* next2 = (unsigned long long*)(ws + alloc((size_t)E * 8));

    const int row_tiles   = (N + 15) / 16;
    const int row_groups  = (row_tiles + 7) / 8;
    const int quads       = N * 128 / 4;
    const int conv_items  = quads + 143360 + N;
    const int scat_blocks = (E + 511) / 512;
    const int gemm_blocks = row_groups * 4;
    int grid3 = scat_blocks * 3;
    int need_g = ((gemm_blocks + 1) / 2) * 3;
    if (need_g > grid3) grid3 = need_g;

    k_convert<<<(conv_items + 255) / 256, 256, 0, stream>>>(
        x, W_edge, W_node, W_ed, W_f1, xb, WE2T, WnT, WdT, Wf1T, head,
        quads, N);
    k_sg<<<grid3, 512, 0, stream>>>(
        src, dst, head, next2, xb, WE2T, b_edge, T, E, N, row_tiles,
        scat_blocks, gemm_blocks);
    k_gather<<<(N + 15) / 16, 256, 0, stream>>>(T, xb, XA, head, next2, N);
    k_tail<<<(row_tiles + 3) / 4, 256, 0, stream>>>(
        T, XA, WnT, WdT, Wf1T, b_node, b_ed, b_f1, W_f2, b_f2,
        (float*)d_out, N, row_tiles);
}